// Round 3
// baseline (138.543 us; speedup 1.0000x reference)
//
#include <hip/hip_runtime.h>
#include <stdint.h>

#define HW 4194304      // 2048*2048
#define WIDTH 2048
#define F(x) ((float)(x))   // double literal -> f32, exactly like numpy scalar promotion

// ---------------------------------------------------------------------------
// Bit-exact replication of glibc sysdeps/ieee754/flt-32/s_cbrtf.c (pre-2.41),
// which is what np.cbrt(float32) resolves to via libm on the host.
// Quadratic double poly -> float u; float t2 = u*u*u (two f32 roundings);
// Halley step entirely in double with DOUBLE factor table; one round to
// float; exact pow2 scale. No FMA anywhere (baseline x86-64 glibc is SSE2).
// Only called for x in (0.008856, ~1.05): positive, normal.
// ---------------------------------------------------------------------------
__device__ __forceinline__ float cbrtf_glibc(float x) {
    // frexpf for positive normal x: xm in [0.5, 1), x = xm * 2^xe
    unsigned int bits = __float_as_uint(x);
    int xe = (int)((bits >> 23) & 0xFF) - 126;
    float xm = __uint_as_float((bits & 0x007FFFFFu) | 0x3F000000u);

    // factor entries exactly as glibc computes them at compile time
    static const double factor[5] = {
        1.0 / 1.5874010519681994748,   // 1 / 2^(2/3)
        1.0 / 1.2599210498948731648,   // 1 / 2^(1/3)
        1.0,
        1.2599210498948731648,         // 2^(1/3)
        1.5874010519681994748          // 2^(2/3)
    };

    double xmd = (double)xm;
    // u = (float)(0.4926... + (0.6975... - 0.1915...*xm)*xm)   [double arith]
    double p = __dsub_rn(0.697570460207922770, __dmul_rn(0.191502161678719066, xmd));
    p = __dadd_rn(0.492659620528969547, __dmul_rn(p, xmd));
    float u = (float)p;

    float t2 = __fmul_rn(__fmul_rn(u, u), u);   // float, two roundings (as glibc)

    double ud  = (double)u;
    double t2d = (double)t2;
    // ym = (float)( u*(t2 + 2*xm) / (2*t2 + xm) * factor[2 + xe%3] )  [double]
    double num = __dmul_rn(ud, __dadd_rn(t2d, __dmul_rn(2.0, xmd)));
    double den = __dadd_rn(__dmul_rn(2.0, t2d), xmd);
    double ym  = __dmul_rn(__ddiv_rn(num, den), factor[2 + (xe % 3)]);
    float ymf = (float)ym;

    return ldexpf(ymf, xe / 3);   // scalbnf; trunc division, exact pow2 scale
}

// Forward RGB -> (L8, a, b). Bit-compatible with numpy f32 evaluation:
// sequential einsum order, no FMA contraction, IEEE divides, glibc cbrtf, rint.
__device__ __forceinline__ void rgb2lab_px(float r, float g, float b,
                                           int& l8, float& A_, float& B_) {
    float X = __fadd_rn(__fadd_rn(__fmul_rn(r, F(0.412453)), __fmul_rn(g, F(0.357580))), __fmul_rn(b, F(0.180423)));
    float Y = __fadd_rn(__fadd_rn(__fmul_rn(r, F(0.212671)), __fmul_rn(g, F(0.715160))), __fmul_rn(b, F(0.072169)));
    float Z = __fadd_rn(__fadd_rn(__fmul_rn(r, F(0.019334)), __fmul_rn(g, F(0.119193))), __fmul_rn(b, F(0.950227)));
    X = __fdiv_rn(X, F(0.950456));
    // Y / 1.0 is bitwise identity
    Z = __fdiv_rn(Z, F(1.088754));
    const float EPS = F(0.008856);
    const float C0  = F(16.0 / 116.0);
    float fx = (X > EPS) ? cbrtf_glibc(X) : __fadd_rn(__fmul_rn(F(7.787), X), C0);
    float fy = (Y > EPS) ? cbrtf_glibc(Y) : __fadd_rn(__fmul_rn(F(7.787), Y), C0);
    float fz = (Z > EPS) ? cbrtf_glibc(Z) : __fadd_rn(__fmul_rn(F(7.787), Z), C0);
    float L  = __fsub_rn(__fmul_rn(F(116.0), fy), F(16.0));
    A_ = __fmul_rn(F(500.0), __fsub_rn(fx, fy));
    B_ = __fmul_rn(F(200.0), __fsub_rn(fy, fz));
    float Lr = rintf(__fmul_rn(L, F(255.0 / 100.0)));   // rintf = round-half-even = np.round
    Lr = fminf(fmaxf(Lr, 0.0f), 255.0f);
    l8 = (int)Lr;
}

// K1: one block per image row. 8 tiles/row * 256 bins in LDS; Lab stored to ws.
__global__ __launch_bounds__(256) void k_hist(const float* __restrict__ x,
        unsigned int* __restrict__ hist,
        float* __restrict__ a_out, float* __restrict__ b_out,
        unsigned char* __restrict__ l8_out, int store) {
    __shared__ unsigned int h[2048];
    const int t = threadIdx.x;
    const int y = blockIdx.x;
    #pragma unroll
    for (int i = 0; i < 8; ++i) h[i * 256 + t] = 0;
    __syncthreads();
    const float* R  = x;
    const float* G  = x + HW;
    const float* Bp = x + 2 * HW;
    const int rowbase = y * WIDTH;
    #pragma unroll
    for (int c = 0; c < 8; ++c) {
        int col = c * 256 + t;
        int idx = rowbase + col;
        float r = R[idx], g = G[idx], b = Bp[idx];
        int l8; float A_, B_;
        rgb2lab_px(r, g, b, l8, A_, B_);
        if (store) {
            a_out[idx]  = A_;
            b_out[idx]  = B_;
            l8_out[idx] = (unsigned char)l8;
        }
        atomicAdd(&h[((col >> 8) << 8) + l8], 1u);
    }
    __syncthreads();
    const int tilerow = y >> 8;
    unsigned int* gh = hist + tilerow * 2048;
    #pragma unroll
    for (int i = 0; i < 8; ++i) {
        unsigned int v = h[i * 256 + t];
        if (v) atomicAdd(&gh[i * 256 + t], v);
    }
}

// K2: one block per tile. Clip + redistribute excess + sequential cumsum + round.
// (cdf partial sums are exact in f32: multiples of 2^-8 below 2^16 -> 24 bits.)
__global__ __launch_bounds__(256) void k_lut(const unsigned int* __restrict__ hist,
                                             float* __restrict__ lut) {
    __shared__ float sh[256];
    __shared__ float hc[256];
    const int t = threadIdx.x;
    const int tile = blockIdx.x;
    float h = (float)hist[tile * 256 + t];
    sh[t] = fmaxf(h - 2560.0f, 0.0f);     // clip = 10*65536/256 = 2560 exactly
    __syncthreads();
    for (int s = 128; s > 0; s >>= 1) {   // integer-valued -> exact in any order
        if (t < s) sh[t] += sh[t + s];
        __syncthreads();
    }
    float excess = sh[0];
    hc[t] = __fadd_rn(fminf(h, 2560.0f), __fmul_rn(excess, F(1.0 / 256.0)));  // /256 exact
    __syncthreads();
    if (t == 0) {
        float c = 0.0f;
        for (int i = 0; i < 256; ++i) { c = __fadd_rn(c, hc[i]); hc[i] = c; }
    }
    __syncthreads();
    float v = rintf(__fmul_rn(hc[t], F(255.0 / 65536.0)));  // 255/65536 exact in f32
    lut[tile * 256 + t] = fminf(fmaxf(v, 0.0f), 255.0f);
}

// K3: per-pixel bilinear LUT interp + Lab -> RGB, CHW coalesced writes.
__global__ __launch_bounds__(256) void k_apply(const float* __restrict__ x,
        const float* __restrict__ lut,
        const float* __restrict__ a_in, const float* __restrict__ b_in,
        const unsigned char* __restrict__ l8_in,
        float* __restrict__ out, int stored) {
    const int idx = blockIdx.x * 256 + threadIdx.x;
    const int y  = idx >> 11;
    const int xc = idx & 2047;
    int l8; float A_, B_;
    if (stored) {
        l8 = (int)l8_in[idx];
        A_ = a_in[idx];
        B_ = b_in[idx];
    } else {
        float r = x[idx], g = x[idx + HW], b = x[idx + 2 * HW];
        rgb2lab_px(r, g, b, l8, A_, B_);
    }
    // tile-interp coordinates: (p+0.5)/256 - 0.5, clipped to [0,7] (exact f32)
    float fyc = fminf(fmaxf(((float)y  + 0.5f) * (1.0f / 256.0f) - 0.5f, 0.0f), 7.0f);
    float fxc = fminf(fmaxf(((float)xc + 0.5f) * (1.0f / 256.0f) - 0.5f, 0.0f), 7.0f);
    int y0 = (int)floorf(fyc); int y1 = min(y0 + 1, 7);
    int x0 = (int)floorf(fxc); int x1 = min(x0 + 1, 7);
    float wy = fyc - (float)y0;
    float wx = fxc - (float)x0;
    float g00 = lut[(y0 * 8 + x0) * 256 + l8];
    float g01 = lut[(y0 * 8 + x1) * 256 + l8];
    float g10 = lut[(y1 * 8 + x0) * 256 + l8];
    float g11 = lut[(y1 * 8 + x1) * 256 + l8];
    float top = __fadd_rn(__fmul_rn(__fsub_rn(1.0f, wx), g00), __fmul_rn(wx, g01));
    float bot = __fadd_rn(__fmul_rn(__fsub_rn(1.0f, wx), g10), __fmul_rn(wx, g11));
    float Leq = __fmul_rn(__fadd_rn(__fmul_rn(__fsub_rn(1.0f, wy), top), __fmul_rn(wy, bot)),
                          F(100.0 / 255.0));
    // lab2rgb
    const float EPS = F(0.008856);
    const float C0  = F(16.0 / 116.0);
    float fy2 = __fdiv_rn(__fadd_rn(Leq, 16.0f), 116.0f);
    float fx2 = __fadd_rn(fy2, __fdiv_rn(A_, 500.0f));
    float fz2 = __fsub_rn(fy2, __fdiv_rn(B_, 200.0f));
    float t3;
    t3 = fx2 * fx2 * fx2;
    float X = ((t3 > EPS) ? t3 : __fdiv_rn(__fsub_rn(fx2, C0), F(7.787))) * F(0.950456);
    t3 = fy2 * fy2 * fy2;
    float Y = ((t3 > EPS) ? t3 : __fdiv_rn(__fsub_rn(fy2, C0), F(7.787))) * F(1.0);
    t3 = fz2 * fz2 * fz2;
    float Z = ((t3 > EPS) ? t3 : __fdiv_rn(__fsub_rn(fz2, C0), F(7.787))) * F(1.088754);
    float rr = __fadd_rn(__fadd_rn(__fmul_rn(X, F(3.240479)),  __fmul_rn(Y, F(-1.537150))), __fmul_rn(Z, F(-0.498535)));
    float gg = __fadd_rn(__fadd_rn(__fmul_rn(X, F(-0.969256)), __fmul_rn(Y, F(1.875992))),  __fmul_rn(Z, F(0.041556)));
    float bb = __fadd_rn(__fadd_rn(__fmul_rn(X, F(0.055648)),  __fmul_rn(Y, F(-0.204043))), __fmul_rn(Z, F(1.057311)));
    rr = fminf(fmaxf(rr, 0.0f), 1.0f);
    gg = fminf(fmaxf(gg, 0.0f), 1.0f);
    bb = fminf(fmaxf(bb, 0.0f), 1.0f);
    out[idx]          = rr;
    out[idx + HW]     = gg;
    out[idx + 2 * HW] = bb;
}

extern "C" void kernel_launch(void* const* d_in, const int* in_sizes, int n_in,
                              void* d_out, int out_size, void* d_ws, size_t ws_size,
                              hipStream_t stream) {
    const float* x = (const float*)d_in[0];
    float* out = (float*)d_out;
    char* ws = (char*)d_ws;
    unsigned int* hist = (unsigned int*)ws;            // 64*256*4   = 64 KiB
    float* lut = (float*)(ws + 65536);                 // 64*256*4   = 64 KiB
    const size_t off = 131072;
    float* a_buf = (float*)(ws + off);                 // 16 MiB
    float* b_buf = (float*)(ws + off + (size_t)HW * 4);// 16 MiB
    unsigned char* l8_buf = (unsigned char*)(ws + off + (size_t)HW * 8); // 4 MiB
    const size_t need = off + (size_t)HW * 9;
    const int store = (ws_size >= need) ? 1 : 0;

    hipMemsetAsync(hist, 0, 65536, stream);
    k_hist<<<2048, 256, 0, stream>>>(x, hist, a_buf, b_buf, l8_buf, store);
    k_lut<<<64, 256, 0, stream>>>(hist, lut);
    k_apply<<<HW / 256, 256, 0, stream>>>(x, lut, a_buf, b_buf, l8_buf, out, store);
}

// Round 7
// 135.466 us; speedup vs baseline: 1.0227x; 1.0227x over previous
//
#include <hip/hip_runtime.h>
#include <stdint.h>

#define HW 4194304      // 2048*2048
#define WIDTH 2048
#define F(x) ((float)(x))   // double literal -> f32, exactly like numpy scalar promotion

// ---------------------------------------------------------------------------
// Bit-exact replication of glibc sysdeps/ieee754/flt-32/s_cbrtf.c (pre-2.41)
// — what np.cbrt(float32) resolves to on the host. EMPIRICAL RULE (R2/R5/R6
// vs R3): ALL THREE channels (fx, fy, fz) must use this exact path; any
// deviation in fx/fz fails at absmax 2.73e-2 even though the perturbation
// model says it shouldn't. Do not substitute HW transcendentals here.
// ---------------------------------------------------------------------------
__device__ __forceinline__ float cbrtf_glibc(float x) {
    unsigned int bits = __float_as_uint(x);
    int xe = (int)((bits >> 23) & 0xFF) - 126;
    float xm = __uint_as_float((bits & 0x007FFFFFu) | 0x3F000000u);

    static const double factor[5] = {
        1.0 / 1.5874010519681994748,   // 1 / 2^(2/3)
        1.0 / 1.2599210498948731648,   // 1 / 2^(1/3)
        1.0,
        1.2599210498948731648,         // 2^(1/3)
        1.5874010519681994748          // 2^(2/3)
    };

    double xmd = (double)xm;
    double p = __dsub_rn(0.697570460207922770, __dmul_rn(0.191502161678719066, xmd));
    p = __dadd_rn(0.492659620528969547, __dmul_rn(p, xmd));
    float u = (float)p;

    float t2 = __fmul_rn(__fmul_rn(u, u), u);   // float, two roundings (as glibc)

    double ud  = (double)u;
    double t2d = (double)t2;
    double num = __dmul_rn(ud, __dadd_rn(t2d, __dmul_rn(2.0, xmd)));
    double den = __dadd_rn(__dmul_rn(2.0, t2d), xmd);
    double ym  = __dmul_rn(__ddiv_rn(num, den), factor[2 + (xe % 3)]);
    float ymf = (float)ym;

    return ldexpf(ymf, xe / 3);
}

// Exact forward path — the ONLY forward path (see empirical rule above).
__device__ __forceinline__ void rgb2lab_px(float r, float g, float b,
                                           int& l8, float& A_, float& B_) {
    float X = __fadd_rn(__fadd_rn(__fmul_rn(r, F(0.412453)), __fmul_rn(g, F(0.357580))), __fmul_rn(b, F(0.180423)));
    float Y = __fadd_rn(__fadd_rn(__fmul_rn(r, F(0.212671)), __fmul_rn(g, F(0.715160))), __fmul_rn(b, F(0.072169)));
    float Z = __fadd_rn(__fadd_rn(__fmul_rn(r, F(0.019334)), __fmul_rn(g, F(0.119193))), __fmul_rn(b, F(0.950227)));
    X = __fdiv_rn(X, F(0.950456));
    Z = __fdiv_rn(Z, F(1.088754));
    const float EPS = F(0.008856);
    const float C0  = F(16.0 / 116.0);
    float fx = (X > EPS) ? cbrtf_glibc(X) : __fadd_rn(__fmul_rn(F(7.787), X), C0);
    float fy = (Y > EPS) ? cbrtf_glibc(Y) : __fadd_rn(__fmul_rn(F(7.787), Y), C0);
    float fz = (Z > EPS) ? cbrtf_glibc(Z) : __fadd_rn(__fmul_rn(F(7.787), Z), C0);
    float L  = __fsub_rn(__fmul_rn(F(116.0), fy), F(16.0));
    A_ = __fmul_rn(F(500.0), __fsub_rn(fx, fy));
    B_ = __fmul_rn(F(200.0), __fsub_rn(fy, fz));
    float Lr = rintf(__fmul_rn(L, F(255.0 / 100.0)));
    Lr = fminf(fmaxf(Lr, 0.0f), 255.0f);
    l8 = (int)Lr;
}

// K1: one block per image row. 8 tiles/row * 256 bins in LDS; Lab -> ws.
__global__ __launch_bounds__(256) void k_hist(const float* __restrict__ x,
        unsigned int* __restrict__ hist,
        float2* __restrict__ ab_out,
        unsigned char* __restrict__ l8_out, int store) {
    __shared__ unsigned int h[2048];
    const int t = threadIdx.x;
    const int y = blockIdx.x;
    #pragma unroll
    for (int i = 0; i < 8; ++i) h[i * 256 + t] = 0;
    __syncthreads();
    const float* R  = x;
    const float* G  = x + HW;
    const float* Bp = x + 2 * HW;
    const int rowbase = y * WIDTH;
    #pragma unroll
    for (int c = 0; c < 8; ++c) {
        int col = c * 256 + t;
        int idx = rowbase + col;
        float r = R[idx], g = G[idx], b = Bp[idx];
        int l8; float A_, B_;
        rgb2lab_px(r, g, b, l8, A_, B_);
        if (store) {
            ab_out[idx] = make_float2(A_, B_);
            l8_out[idx] = (unsigned char)l8;
        }
        atomicAdd(&h[((col >> 8) << 8) + l8], 1u);
    }
    __syncthreads();
    const int tilerow = y >> 8;
    unsigned int* gh = hist + tilerow * 2048;
    #pragma unroll
    for (int i = 0; i < 8; ++i) {
        unsigned int v = h[i * 256 + t];
        if (v) atomicAdd(&gh[i * 256 + t], v);
    }
}

// K2: one block per tile. Clip + redistribute + sequential cumsum + round.
// (cdf partial sums exact in f32: multiples of 2^-8 below 2^16.)
__global__ __launch_bounds__(256) void k_lut(const unsigned int* __restrict__ hist,
                                             float* __restrict__ lut) {
    __shared__ float sh[256];
    __shared__ float hc[256];
    const int t = threadIdx.x;
    const int tile = blockIdx.x;
    float h = (float)hist[tile * 256 + t];
    sh[t] = fmaxf(h - 2560.0f, 0.0f);     // clip = 10*65536/256 = 2560 exactly
    __syncthreads();
    for (int s = 128; s > 0; s >>= 1) {
        if (t < s) sh[t] += sh[t + s];
        __syncthreads();
    }
    float excess = sh[0];
    hc[t] = __fadd_rn(fminf(h, 2560.0f), __fmul_rn(excess, F(1.0 / 256.0)));
    __syncthreads();
    if (t == 0) {
        float c = 0.0f;
        for (int i = 0; i < 256; ++i) { c = __fadd_rn(c, hc[i]); hc[i] = c; }
    }
    __syncthreads();
    float v = rintf(__fmul_rn(hc[t], F(255.0 / 65536.0)));
    lut[tile * 256 + t] = fminf(fmaxf(v, 0.0f), 255.0f);
}

// K3: one block per row. Stage the 2 needed LUT tile-rows (16 KB) in LDS,
// gather from LDS (random l8 ~2-way bank aliasing = free), Lab -> RGB.
__global__ __launch_bounds__(256) void k_apply(const float* __restrict__ x,
        const float* __restrict__ lut,
        const float2* __restrict__ ab_in,
        const unsigned char* __restrict__ l8_in,
        float* __restrict__ out, int stored) {
    __shared__ float lutS[4096];   // [2][8][256]: top row y0, bottom row y1
    const int t = threadIdx.x;
    const int y = blockIdx.x;

    // block-uniform vertical interp (exact f32: pow2 ops only)
    float fyc = fminf(fmaxf(((float)y + 0.5f) * (1.0f / 256.0f) - 0.5f, 0.0f), 7.0f);
    int y0 = (int)floorf(fyc); int y1 = min(y0 + 1, 7);
    float wy = __fsub_rn(fyc, (float)y0);
    float omwy = __fsub_rn(1.0f, wy);

    const float* ltop = lut + y0 * 2048;
    const float* lbot = lut + y1 * 2048;
    #pragma unroll
    for (int i = 0; i < 8; ++i) {
        lutS[i * 256 + t]        = ltop[i * 256 + t];
        lutS[2048 + i * 256 + t] = lbot[i * 256 + t];
    }
    __syncthreads();

    const int rowbase = y * WIDTH;
    #pragma unroll
    for (int c = 0; c < 8; ++c) {
        int col = c * 256 + t;
        int idx = rowbase + col;
        int l8; float A_, B_;
        if (stored) {
            float2 ab = ab_in[idx];
            A_ = ab.x; B_ = ab.y;
            l8 = (int)l8_in[idx];
        } else {
            float r = x[idx], g = x[idx + HW], b = x[idx + 2 * HW];
            rgb2lab_px(r, g, b, l8, A_, B_);
        }
        float fxc = fminf(fmaxf(((float)col + 0.5f) * (1.0f / 256.0f) - 0.5f, 0.0f), 7.0f);
        int x0 = (int)floorf(fxc); int x1 = min(x0 + 1, 7);
        float wx = __fsub_rn(fxc, (float)x0);
        float omwx = __fsub_rn(1.0f, wx);
        float g00 = lutS[x0 * 256 + l8];
        float g01 = lutS[x1 * 256 + l8];
        float g10 = lutS[2048 + x0 * 256 + l8];
        float g11 = lutS[2048 + x1 * 256 + l8];
        float top = __fadd_rn(__fmul_rn(omwx, g00), __fmul_rn(wx, g01));
        float bot = __fadd_rn(__fmul_rn(omwx, g10), __fmul_rn(wx, g11));
        float Leq = __fmul_rn(__fadd_rn(__fmul_rn(omwy, top), __fmul_rn(wy, bot)),
                              F(100.0 / 255.0));
        // lab2rgb
        const float EPS = F(0.008856);
        const float C0  = F(16.0 / 116.0);
        float fy2 = __fdiv_rn(__fadd_rn(Leq, 16.0f), 116.0f);
        float fx2 = __fadd_rn(fy2, __fdiv_rn(A_, 500.0f));
        float fz2 = __fsub_rn(fy2, __fdiv_rn(B_, 200.0f));
        float t3;
        t3 = fx2 * fx2 * fx2;
        float X = ((t3 > EPS) ? t3 : __fdiv_rn(__fsub_rn(fx2, C0), F(7.787))) * F(0.950456);
        t3 = fy2 * fy2 * fy2;
        float Y = ((t3 > EPS) ? t3 : __fdiv_rn(__fsub_rn(fy2, C0), F(7.787))) * F(1.0);
        t3 = fz2 * fz2 * fz2;
        float Z = ((t3 > EPS) ? t3 : __fdiv_rn(__fsub_rn(fz2, C0), F(7.787))) * F(1.088754);
        float rr = __fadd_rn(__fadd_rn(__fmul_rn(X, F(3.240479)),  __fmul_rn(Y, F(-1.537150))), __fmul_rn(Z, F(-0.498535)));
        float gg = __fadd_rn(__fadd_rn(__fmul_rn(X, F(-0.969256)), __fmul_rn(Y, F(1.875992))),  __fmul_rn(Z, F(0.041556)));
        float bb = __fadd_rn(__fadd_rn(__fmul_rn(X, F(0.055648)),  __fmul_rn(Y, F(-0.204043))), __fmul_rn(Z, F(1.057311)));
        rr = fminf(fmaxf(rr, 0.0f), 1.0f);
        gg = fminf(fmaxf(gg, 0.0f), 1.0f);
        bb = fminf(fmaxf(bb, 0.0f), 1.0f);
        out[idx]          = rr;
        out[idx + HW]     = gg;
        out[idx + 2 * HW] = bb;
    }
}

extern "C" void kernel_launch(void* const* d_in, const int* in_sizes, int n_in,
                              void* d_out, int out_size, void* d_ws, size_t ws_size,
                              hipStream_t stream) {
    const float* x = (const float*)d_in[0];
    float* out = (float*)d_out;
    char* ws = (char*)d_ws;
    unsigned int* hist = (unsigned int*)ws;            // 64*256*4 = 64 KiB
    float* lut = (float*)(ws + 65536);                 // 64*256*4 = 64 KiB
    const size_t off = 131072;
    float2* ab_buf = (float2*)(ws + off);              // 32 MiB
    unsigned char* l8_buf = (unsigned char*)(ws + off + (size_t)HW * 8); // 4 MiB
    const size_t need = off + (size_t)HW * 9;
    const int store = (ws_size >= need) ? 1 : 0;

    (void)hipMemsetAsync(hist, 0, 65536, stream);
    k_hist<<<2048, 256, 0, stream>>>(x, hist, ab_buf, l8_buf, store);
    k_lut<<<64, 256, 0, stream>>>(hist, lut);
    k_apply<<<2048, 256, 0, stream>>>(x, lut, ab_buf, l8_buf, out, store);
}